// Round 3
// baseline (830.750 us; speedup 1.0000x reference)
//
#include <hip/hip_runtime.h>
#include <hip/hip_cooperative_groups.h>
#include <math.h>

namespace cg = cooperative_groups;

#define BB 64
#define SS 2048
#define HH 1024
#define LL 15
#define LSTR 68  // LDS leading stride: 68*4=272 B (16B-aligned, breaks pow2 bank stride)

// ---- 64x64 GEMM tile: C[0:64, j0:j0+64] += A[0:64,k0:kend] @ W[k0:kend, j0:j0+64]
// 256 threads as 16x16, 4x4 micro-tile each; k-major LDS; register double-buffer.
__device__ __forceinline__ void gemm_tile_body(
    float* __restrict__ As, float* __restrict__ Ws,
    const float* __restrict__ A, int lda,
    const float* __restrict__ W, int ldw,
    const float* __restrict__ bias,
    float* __restrict__ C, int ldc,
    int k0, int kend, int j0, bool addBias) {
  int tid = threadIdx.x;
  int tx = tid & 15, ty = tid >> 4;

  float4 aReg[2], wReg[2];
  int aRow[2], aKq[2], wRow[2], wCq[2];
#pragma unroll
  for (int i = 0; i < 2; ++i) {
    int idx = tid + i * 256;
    aRow[i] = idx & 63; aKq[i] = idx >> 6;   // A: row-major, float4 over k
    wRow[i] = idx >> 4; wCq[i] = idx & 15;   // W: row-major, float4 over cols
  }

  auto loadRegs = [&](int kb) {
#pragma unroll
    for (int i = 0; i < 2; ++i) {
      aReg[i] = *(const float4*)&A[(size_t)aRow[i] * lda + kb + 4 * aKq[i]];
      wReg[i] = *(const float4*)&W[(size_t)(kb + wRow[i]) * ldw + j0 + 4 * wCq[i]];
    }
  };

  float acc[4][4] = {{0.f}};
  loadRegs(k0);
  for (int kb = k0; kb < kend; kb += 32) {
#pragma unroll
    for (int i = 0; i < 2; ++i) {
      float av[4] = {aReg[i].x, aReg[i].y, aReg[i].z, aReg[i].w};
#pragma unroll
      for (int j = 0; j < 4; ++j) As[(4 * aKq[i] + j) * LSTR + aRow[i]] = av[j];
      *(float4*)&Ws[wRow[i] * LSTR + 4 * wCq[i]] = wReg[i];
    }
    __syncthreads();
    if (kb + 32 < kend) loadRegs(kb + 32);  // prefetch next k-block
#pragma unroll
    for (int kk = 0; kk < 32; ++kk) {
      float4 a4 = *(const float4*)&As[kk * LSTR + ty * 4];
      float4 w4 = *(const float4*)&Ws[kk * LSTR + tx * 4];
      float a[4] = {a4.x, a4.y, a4.z, a4.w};
      float w[4] = {w4.x, w4.y, w4.z, w4.w};
#pragma unroll
      for (int i = 0; i < 4; ++i)
#pragma unroll
        for (int j = 0; j < 4; ++j) acc[i][j] += a[i] * w[j];
    }
    __syncthreads();
  }
#pragma unroll
  for (int i = 0; i < 4; ++i) {
    int r = ty * 4 + i;
#pragma unroll
    for (int j = 0; j < 4; ++j) {
      int c = j0 + tx * 4 + j;
      float v = acc[i][j];
      if (addBias) v += bias[c];
      atomicAdd(&C[(size_t)r * ldc + c], v);
    }
  }
}

// ---- single fused cooperative kernel: all 5 stages with grid.sync() between
__global__ void __launch_bounds__(256, 1) fused_kernel(
    const float* __restrict__ x, const int* __restrict__ eidx,
    const float* __restrict__ W_cls, const float* __restrict__ b_cls,
    const float* __restrict__ W_e1, const float* __restrict__ b_e1,
    const float* __restrict__ W_e2, const float* __restrict__ b_e2,
    const float* __restrict__ W1, const float* __restrict__ b1,
    const float* __restrict__ W2, const float* __restrict__ b2,
    const float* __restrict__ Wout, const float* __restrict__ bout,
    float* __restrict__ t_cat, float* __restrict__ h_cat,
    float* __restrict__ h1, float* __restrict__ h2,
    float* __restrict__ out) {
  cg::grid_group grid = cg::this_grid();
  __shared__ float smem[2 * 32 * LSTR];
  float* As = smem;
  float* Ws = smem + 32 * LSTR;
  int r = blockIdx.x;     // 0..255
  int tid = threadIdx.x;  // 0..255

  // ---------- stage 0: span means + tanh; zero h_cat/h1/h2 ----------
  {
    int b = r >> 2, hc = r & 3;
    int h = hc * 256 + tid;
    float* z = h_cat + (size_t)b * 3 * HH + hc * 768;
    for (int i = tid; i < 768; i += 256) z[i] = 0.f;
    h1[(size_t)b * HH + h] = 0.f;
    h2[(size_t)b * HH + h] = 0.f;

    int s1 = eidx[b * 4 + 0], e1 = eidx[b * 4 + 1];
    int s2 = eidx[b * 4 + 2], e2 = eidx[b * 4 + 3];
    float c1 = (float)max(e1 - s1, 1);
    float c2 = (float)max(e2 - s2, 1);
    const float* xb = x + (size_t)b * SS * HH;
    float* tb = t_cat + (size_t)b * 3 * HH;
    float v0 = xb[h];
    float a1 = 0.f, a2 = 0.f;
    for (int s = s1; s < e1; ++s) a1 += xb[(size_t)s * HH + h];
    for (int s = s2; s < e2; ++s) a2 += xb[(size_t)s * HH + h];
    tb[h]          = tanhf(v0);
    tb[HH + h]     = tanhf(a1 / c1);
    tb[2 * HH + h] = tanhf(a2 / c2);
  }
  grid.sync();

  // ---------- stage 1: block-diag [64,3072] -> [64,3072]; 192 blocks, KS=4 ----------
  if (r < 192) {
    int zb = r >> 6;            // branch 0..2
    int rem = r & 63;
    int jt = rem & 15;          // j-tile
    int ks = rem >> 4;          // k-split 0..3, Kchunk=256
    const float* W = (zb == 0) ? W_cls : ((zb == 1) ? W_e1 : W_e2);
    const float* bias = (zb == 0) ? b_cls : ((zb == 1) ? b_e1 : b_e2);
    gemm_tile_body(As, Ws, t_cat + zb * HH, 3 * HH, W, HH, bias,
                   h_cat + zb * HH, 3 * HH,
                   ks * 256, ks * 256 + 256, jt * 64, ks == 0);
  }
  grid.sync();

  // ---------- stage 2: [64,3072] @ [3072,1024]; 256 blocks, KS=16, Kchunk=192 ----------
  {
    int jt = r & 15, ks = r >> 4;
    gemm_tile_body(As, Ws, h_cat, 3 * HH, W1, HH, b1, h1, HH,
                   ks * 192, ks * 192 + 192, jt * 64, ks == 0);
  }
  grid.sync();

  // ---------- stage 3: [64,1024] @ [1024,1024]; 256 blocks, KS=16, Kchunk=64 ----------
  {
    int jt = r & 15, ks = r >> 4;
    gemm_tile_body(As, Ws, h1, HH, W2, HH, b2, h2, HH,
                   ks * 64, ks * 64 + 64, jt * 64, ks == 0);
  }
  grid.sync();

  // ---------- stage 4: [64,1024] @ [1024,15]; wave-per-output ----------
  {
    int lane = tid & 63;
    int idx = r * 4 + (tid >> 6);
    if (idx < BB * LL) {
      int b = idx / LL, l = idx % LL;
      const float* h = h2 + (size_t)b * HH;
      float acc = 0.f;
#pragma unroll
      for (int w = 0; w < 4; ++w) {
        int k0 = (w * 64 + lane) * 4;
        float4 h4 = *(const float4*)&h[k0];
        acc += h4.x * Wout[(size_t)(k0 + 0) * LL + l];
        acc += h4.y * Wout[(size_t)(k0 + 1) * LL + l];
        acc += h4.z * Wout[(size_t)(k0 + 2) * LL + l];
        acc += h4.w * Wout[(size_t)(k0 + 3) * LL + l];
      }
#pragma unroll
      for (int off = 32; off > 0; off >>= 1) acc += __shfl_down(acc, off, 64);
      if (lane == 0) out[idx] = acc + bout[l];
    }
  }
}

extern "C" void kernel_launch(void* const* d_in, const int* in_sizes, int n_in,
                              void* d_out, int out_size, void* d_ws, size_t ws_size,
                              hipStream_t stream) {
  const float* x     = (const float*)d_in[0];
  const int*   eidx  = (const int*)d_in[1];
  const float* W_cls = (const float*)d_in[2];
  const float* b_cls = (const float*)d_in[3];
  const float* W_e1  = (const float*)d_in[4];
  const float* b_e1  = (const float*)d_in[5];
  const float* W_e2  = (const float*)d_in[6];
  const float* b_e2  = (const float*)d_in[7];
  const float* W1    = (const float*)d_in[8];
  const float* b1    = (const float*)d_in[9];
  const float* W2    = (const float*)d_in[10];
  const float* b2    = (const float*)d_in[11];
  const float* Wout  = (const float*)d_in[12];
  const float* bout  = (const float*)d_in[13];
  float* out = (float*)d_out;

  float* ws    = (float*)d_ws;
  float* t_cat = ws;                          // 64*3072
  float* h_cat = t_cat + BB * 3 * HH;         // 64*3072 (atomic-accumulated)
  float* h1    = h_cat + BB * 3 * HH;         // 64*1024 (atomic-accumulated)
  float* h2    = h1 + BB * HH;                // 64*1024 (atomic-accumulated)

  void* args[] = {
    (void*)&x, (void*)&eidx,
    (void*)&W_cls, (void*)&b_cls, (void*)&W_e1, (void*)&b_e1,
    (void*)&W_e2, (void*)&b_e2, (void*)&W1, (void*)&b1,
    (void*)&W2, (void*)&b2, (void*)&Wout, (void*)&bout,
    (void*)&t_cat, (void*)&h_cat, (void*)&h1, (void*)&h2, (void*)&out
  };
  hipLaunchCooperativeKernel((const void*)fused_kernel,
                             dim3(256), dim3(256), args, 0, stream);
}